// Round 5
// baseline (496.550 us; speedup 1.0000x reference)
//
#include <hip/hip_runtime.h>

typedef unsigned short u16;
typedef __attribute__((ext_vector_type(8))) short short8;
typedef __attribute__((ext_vector_type(4))) float fx4;
typedef __attribute__((ext_vector_type(4))) int ix4;
typedef __attribute__((ext_vector_type(4))) unsigned short ux4;

__device__ __forceinline__ float bf2f(u16 h) {
  union { unsigned u; float f; } a; a.u = ((unsigned)h) << 16; return a.f;
}
__device__ __forceinline__ u16 f2bf(float f) {
  union { float f; unsigned u; } a; a.f = f;
  unsigned u = a.u;
  return (u16)((u + 0x7FFFu + ((u >> 16) & 1u)) >> 16);  // RNE
}

// async global->LDS, 16B per lane. LDS dest must be wave-uniform base + lane*16.
__device__ __forceinline__ void gl_lds(const u16* g, u16* l) {
  __builtin_amdgcn_global_load_lds(
      (const __attribute__((address_space(1))) unsigned*)g,
      (__attribute__((address_space(3))) unsigned*)l, 16, 0, 0);
}

constexpr int S_LEN = 2048;
constexpr int DM = 2048;
constexpr int HD = 128;
constexpr int NH = 16;
constexpr float NEG = -1.0e9f;
constexpr float SC2 = 0.08838834764831845f * 1.4426950408889634f;  // 1/sqrt(128)*log2(e)
constexpr float INV2PI = 0.15915494309189535f;

// HW sin/cos: input pre-reduced to revolutions in [0,1).
// |angle| <= 2048 rad -> 326 rev; f32 fract error ~3e-5 rev ~ 2e-4 rad,
// far below the bf16 output quantization (2^-8 relative).
__device__ __forceinline__ void fast_sincos(float rev_unred, float& sn, float& cs) {
  float rev = rev_unred - floorf(rev_unred);
  sn = __builtin_amdgcn_sinf(rev);
  cs = __builtin_amdgcn_cosf(rev);
}

// ---------------------------------------------------------------------------
// fp32 -> bf16 bulk convert (memory-bound)
// ---------------------------------------------------------------------------
__global__ __launch_bounds__(256)
void cvt_kernel(const float* __restrict__ in, u16* __restrict__ out)
{
  int idx = blockIdx.x * 256 + threadIdx.x;
  fx4 v = *(const fx4*)&in[(size_t)idx * 4];
  ux4 pk;
  pk[0] = f2bf(v[0]); pk[1] = f2bf(v[1]); pk[2] = f2bf(v[2]); pk[3] = f2bf(v[3]);
  *(ux4*)&out[(size_t)idx * 4] = pk;
}

// ---------------------------------------------------------------------------
// GEMM: C[M,N] = A[M,K] @ W[N,K]^T + bias (bias fp32)
// MODE 0: fp32 out to o0;  MODE 1: QKV scatter bf16 (o0=Q, o1=K, o2=V^T)
//         with RoPE fused into the Q/K epilogue (HW v_sin/v_cos, not libm).
// Proven 149 us / ~30% MfmaUtil on QKV; two phased-256^2 rewrites both
// regressed -> keep this structure (inter-block overlap does the hiding).
// ---------------------------------------------------------------------------
template<int M, int N, int K, int MODE, bool AB16, bool WB16>
__global__ __launch_bounds__(256)
void gemm_bt(const void* __restrict__ Av, const void* __restrict__ Wv,
             const float* __restrict__ bias,
             void* __restrict__ o0, u16* __restrict__ o1, u16* __restrict__ o2)
{
  constexpr int BK = 64;
  __shared__ u16 la[128 * BK];
  __shared__ u16 lb[128 * BK];
  const int tid  = threadIdx.x;
  const int lane = tid & 63;
  const int wv   = tid >> 6;
  const int wm   = wv >> 1, wn = wv & 1;
  const int quad = lane >> 4, l16 = lane & 15;
  const int m0 = blockIdx.y * 128, n0 = blockIdx.x * 128;
  const int sw = l16 & 7;                     // frag-read swizzle (row&7 = l16&7)

  fx4 acc[4][4] = {};

  for (int k0 = 0; k0 < K; k0 += BK) {
    __syncthreads();
    if constexpr (AB16) {
      const u16* ap = (const u16*)Av + (size_t)m0 * K + k0;
      #pragma unroll
      for (int i = 0; i < 4; ++i) {
        int c = i * 256 + tid, row = c >> 3, cc = c & 7;
        int g = cc ^ (row & 7);
        gl_lds(ap + (size_t)row * K + g * 8, &la[c * 8]);
      }
    } else {
      const float* ap = (const float*)Av + (size_t)m0 * K + k0;
      #pragma unroll
      for (int i = 0; i < 4; ++i) {
        int c = i * 256 + tid, row = c >> 3, cc = c & 7;
        fx4 v0 = *(const fx4*)&ap[(size_t)row * K + cc * 8];
        fx4 v1 = *(const fx4*)&ap[(size_t)row * K + cc * 8 + 4];
        ux4 p0, p1;
        p0[0]=f2bf(v0[0]); p0[1]=f2bf(v0[1]); p0[2]=f2bf(v0[2]); p0[3]=f2bf(v0[3]);
        p1[0]=f2bf(v1[0]); p1[1]=f2bf(v1[1]); p1[2]=f2bf(v1[2]); p1[3]=f2bf(v1[3]);
        int s = cc ^ (row & 7);
        *(ux4*)&la[row * BK + s * 8]     = p0;
        *(ux4*)&la[row * BK + s * 8 + 4] = p1;
      }
    }
    if constexpr (WB16) {
      const u16* wp = (const u16*)Wv + (size_t)n0 * K + k0;
      #pragma unroll
      for (int i = 0; i < 4; ++i) {
        int c = i * 256 + tid, row = c >> 3, cc = c & 7;
        int g = cc ^ (row & 7);
        gl_lds(wp + (size_t)row * K + g * 8, &lb[c * 8]);
      }
    } else {
      const float* wp = (const float*)Wv + (size_t)n0 * K + k0;
      #pragma unroll
      for (int i = 0; i < 4; ++i) {
        int c = i * 256 + tid, row = c >> 3, cc = c & 7;
        fx4 v0 = *(const fx4*)&wp[(size_t)row * K + cc * 8];
        fx4 v1 = *(const fx4*)&wp[(size_t)row * K + cc * 8 + 4];
        ux4 p0, p1;
        p0[0]=f2bf(v0[0]); p0[1]=f2bf(v0[1]); p0[2]=f2bf(v0[2]); p0[3]=f2bf(v0[3]);
        p1[0]=f2bf(v1[0]); p1[1]=f2bf(v1[1]); p1[2]=f2bf(v1[2]); p1[3]=f2bf(v1[3]);
        int s = cc ^ (row & 7);
        *(ux4*)&lb[row * BK + s * 8]     = p0;
        *(ux4*)&lb[row * BK + s * 8 + 4] = p1;
      }
    }
    __syncthreads();
    #pragma unroll
    for (int ks = 0; ks < 2; ++ks) {
      short8 af[4], bfg[4];
      #pragma unroll
      for (int t = 0; t < 4; ++t) {
        int arow = wm * 64 + t * 16 + l16;
        int brow = (t & 2) * 32 + wn * 32 + (t & 1) * 16 + l16;
        int cc = (ks * 4 + quad) ^ sw;
        af[t]  = *(const short8*)&la[arow * BK + cc * 8];
        bfg[t] = *(const short8*)&lb[brow * BK + cc * 8];
      }
      #pragma unroll
      for (int mt = 0; mt < 4; ++mt)
        #pragma unroll
        for (int nt = 0; nt < 4; ++nt)
          acc[mt][nt] = __builtin_amdgcn_mfma_f32_16x16x32_bf16(af[mt], bfg[nt], acc[mt][nt], 0, 0, 0);
    }
  }

  if constexpr (MODE == 0) {
    float* of = (float*)o0;
    #pragma unroll
    for (int nt = 0; nt < 4; ++nt) {
      int col = n0 + (nt & 2) * 32 + wn * 32 + (nt & 1) * 16 + l16;
      float bz = bias[col];
      #pragma unroll
      for (int mt = 0; mt < 4; ++mt) {
        int row = m0 + wm * 64 + mt * 16 + quad * 4;
        #pragma unroll
        for (int r = 0; r < 4; ++r)
          of[(size_t)(row + r) * N + col] = acc[mt][nt][r] + bz;
      }
    }
  } else {
    const int which = n0 >> 11;
    const int head  = (n0 >> 7) & 15;
    const int b     = m0 >> 11;
    const int bh    = b * NH + head;
    if (which == 2) {
      #pragma unroll
      for (int nt = 0; nt < 4; ++nt) {
        int dcol = (nt & 2) * 32 + wn * 32 + (nt & 1) * 16 + l16;
        float bz = bias[n0 + dcol];
        #pragma unroll
        for (int mt = 0; mt < 4; ++mt) {
          int srow = (m0 & (S_LEN - 1)) + wm * 64 + mt * 16 + quad * 4;
          ux4 pk;
          #pragma unroll
          for (int r = 0; r < 4; ++r) pk[r] = f2bf(acc[mt][nt][r] + bz);
          *(ux4*)&o2[((size_t)bh * HD + dcol) * S_LEN + srow] = pk;  // V^T
        }
      }
    } else {
      // Q or K with fused RoPE: pair (i, i+64) = acc[..][nt] / acc[..][nt+2]
      u16* buf = (which == 0) ? (u16*)o0 : o1;
      #pragma unroll
      for (int nt = 0; nt < 2; ++nt) {
        int i = wn * 32 + nt * 16 + l16;            // 0..63
        // invf2 = 10000^(-i/64) / (2*pi): angle in revolutions per srow
        float invf2 = exp2f((float)i * -0.20762050594f) * INV2PI;
        float bz1 = bias[n0 + i];
        float bz2 = bias[n0 + i + 64];
        #pragma unroll
        for (int mt = 0; mt < 4; ++mt) {
          int srow = (m0 & (S_LEN - 1)) + wm * 64 + mt * 16 + quad * 4;
          size_t base = ((size_t)bh * S_LEN + srow) * HD + i;
          #pragma unroll
          for (int r = 0; r < 4; ++r) {
            float sn, cs;
            fast_sincos((float)(srow + r) * invf2, sn, cs);
            float v1 = acc[mt][nt][r] + bz1;
            float v2 = acc[mt][nt + 2][r] + bz2;
            buf[base + (size_t)r * HD]      = f2bf(v1 * cs - v2 * sn);
            buf[base + (size_t)r * HD + 64] = f2bf(v2 * cs + v1 * sn);
          }
        }
      }
    }
  }
}

// ---------------------------------------------------------------------------
// Transposed online-softmax tile step with defer-max (T13). S^T in C-layout:
// lane owns q-row=l16, 16 keys = snt*16 + quad*4 + r in registers. Row reduce
// = in-register tree + 2 shuffles. When the new tile max is within THR=8
// (log2 units) of the running max, skip the O-rescale and keep m (P bounded
// by 2^8; f32 accum has ample headroom; normalization by l stays exact).
// Wave-uniform branch via __all. P -> LDS [q][key], 8B writes.
// ---------------------------------------------------------------------------
__device__ __forceinline__ void soft_tile_t(fx4 s[4], float& m, float& l, fx4* o,
                                            u16* lp, bool mask, int qrow, int k0,
                                            int l16, int quad)
{
  #pragma unroll
  for (int snt = 0; snt < 4; ++snt)
    #pragma unroll
    for (int r = 0; r < 4; ++r) {
      float v = s[snt][r] * SC2;
      if (mask && (k0 + snt * 16 + quad * 4 + r > qrow)) v = NEG;
      s[snt][r] = v;
    }
  float mx = s[0][0];
  #pragma unroll
  for (int snt = 0; snt < 4; ++snt)
    #pragma unroll
    for (int r = 0; r < 4; ++r) mx = fmaxf(mx, s[snt][r]);
  mx = fmaxf(mx, __shfl_xor(mx, 16, 64));
  mx = fmaxf(mx, __shfl_xor(mx, 32, 64));

  const bool defer = __all(mx <= m + 8.f);   // wave-uniform
  float al = 1.f;
  if (!defer) {
    float mn = fmaxf(m, mx);
    al = exp2f(m - mn);
    m = mn;
  }
  float rs = 0.f;
  #pragma unroll
  for (int snt = 0; snt < 4; ++snt)
    #pragma unroll
    for (int r = 0; r < 4; ++r) {
      float pz = exp2f(s[snt][r] - m);
      s[snt][r] = pz;
      rs += pz;
    }
  rs += __shfl_xor(rs, 16, 64);
  rs += __shfl_xor(rs, 32, 64);
  l = l * al + rs;
  if (!defer) {
    #pragma unroll
    for (int nd = 0; nd < 8; ++nd)
      #pragma unroll
      for (int r = 0; r < 4; ++r) o[nd][r] *= al;
  }
  #pragma unroll
  for (int snt = 0; snt < 4; ++snt) {
    ux4 pk;
    #pragma unroll
    for (int r = 0; r < 4; ++r) pk[r] = f2bf(s[snt][r]);
    *(ux4*)&lp[l16 * 72 + snt * 16 + quad * 4] = pk;   // 8B write
  }
}

// ---------------------------------------------------------------------------
// Flash attention (causal), PAIRED q-tiles (p, 31-p) + XCD-aware decode +
// 3 blocks/CU. Transposed pipeline: S^T = K·Q^T and O^T = V^T·P^T.
// Pairing shares each staged K/V tile between two q-tiles (392 vs 528
// tile-stages) and shares the K/V frag ds_reads.
// Grid: flat 512; hardware round-robins w%8 across XCDs -> give each XCD
// 4 consecutive bh (4 MB K/V = one XCD L2): bh=(w&7)*4+((w>>3)>>4),
// p=(w>>3)&15. LDS: K 16K + V^T 16K + 2x per-wave P 9K = 50 KB -> 3 resident
// blocks/CU = 12 waves/CU; inter-block TLP hides stage drain + softmax chain.
// ---------------------------------------------------------------------------
__global__ __launch_bounds__(256, 3)
void attn_kernel(const u16* __restrict__ qbuf, const u16* __restrict__ kbuf,
                 const u16* __restrict__ vtbuf, u16* __restrict__ ctx)
{
  __shared__ u16 lk[64 * 128];     // K tile  [key][d],  swizzled chunks
  __shared__ u16 lv[128 * 64];     // V^T tile [d][key], swizzled chunks
  __shared__ u16 lph[4][16 * 72];  // per-wave P (hi tile) [q][key]
  __shared__ u16 lpl[4][16 * 72];  // per-wave P (lo tile)
  const int tid = threadIdx.x, lane = tid & 63, wv = tid >> 6;
  const int quad = lane >> 4, l16 = lane & 15;
  const int w = blockIdx.x;
  const int bh = (w & 7) * 4 + ((w >> 3) >> 4);   // XCD-grouped head
  const int p  = (w >> 3) & 15;                   // pair index 0..15
  const int qt_lo = p, qt_hi = 31 - p;
  const int head = bh & 15, b = bh >> 4;
  const int s8 = l16 & 7;          // frag-read swizzle index

  short8 qh[4], ql[4];
  {
    const size_t bh_ = ((size_t)bh * S_LEN + qt_hi * 64 + wv * 16 + l16) * HD;
    const size_t bl_ = ((size_t)bh * S_LEN + qt_lo * 64 + wv * 16 + l16) * HD;
    #pragma unroll
    for (int kd = 0; kd < 4; ++kd) {
      qh[kd] = *(const short8*)&qbuf[bh_ + kd * 32 + quad * 8];
      ql[kd] = *(const short8*)&qbuf[bl_ + kd * 32 + quad * 8];
    }
  }

  fx4 oh[8] = {}, ol[8] = {};
  float mh = NEG, lh = 0.f, ml = NEG, llo = 0.f;
  const int qrow_hi = qt_hi * 64 + wv * 16 + l16;
  const int qrow_lo = qt_lo * 64 + wv * 16 + l16;

  for (int kt = 0; kt <= qt_hi; ++kt) {
    const int k0 = kt * 64;
    const bool dlo = (kt <= qt_lo);
    if (kt) __syncthreads();                 // WAR vs previous compute
    {
      const u16* kg = kbuf + ((size_t)bh * S_LEN + k0) * HD;
      const u16* vg = vtbuf + (size_t)bh * HD * S_LEN + k0;
      #pragma unroll
      for (int i = 0; i < 4; ++i) {          // K tile: 64 rows x 16 chunks
        int c = i * 256 + tid;
        int row = c >> 4, cc = c & 15;
        int g = cc ^ (row & 7);
        gl_lds(kg + (size_t)row * HD + g * 8, &lk[c * 8]);
      }
      #pragma unroll
      for (int i = 0; i < 4; ++i) {          // V^T tile: 128 rows x 8 chunks
        int c = i * 256 + tid;
        int row = c >> 3, cc = c & 7;
        int g = cc ^ (row & 7);
        gl_lds(vg + (size_t)row * S_LEN + g * 8, &lv[c * 8]);
      }
    }
    __syncthreads();                         // RAW: drain stage

    // S^T = K·Q^T for both tiles; K-frag (A operand) loaded once
    fx4 sh[4] = {}, sl[4] = {};
    #pragma unroll
    for (int snt = 0; snt < 4; ++snt) {
      #pragma unroll
      for (int kd = 0; kd < 4; ++kd) {
        int cc = (kd * 4 + quad) ^ s8;
        short8 kf = *(const short8*)&lk[(snt * 16 + l16) * 128 + cc * 8];
        sh[snt] = __builtin_amdgcn_mfma_f32_16x16x32_bf16(kf, qh[kd], sh[snt], 0, 0, 0);
        if (dlo)
          sl[snt] = __builtin_amdgcn_mfma_f32_16x16x32_bf16(kf, ql[kd], sl[snt], 0, 0, 0);
      }
    }

    soft_tile_t(sh, mh, lh, oh, lph[wv], kt == qt_hi, qrow_hi, k0, l16, quad);
    if (dlo) soft_tile_t(sl, ml, llo, ol, lpl[wv], kt == qt_lo, qrow_lo, k0, l16, quad);

    // O^T += V^T·P^T for both tiles; V-frag (A operand) loaded once
    #pragma unroll
    for (int kk = 0; kk < 2; ++kk) {
      short8 ph = *(const short8*)&lph[wv][l16 * 72 + kk * 32 + quad * 8];
      short8 pl = *(const short8*)&lpl[wv][l16 * 72 + kk * 32 + quad * 8];
      #pragma unroll
      for (int nd = 0; nd < 8; ++nd) {
        int cc = (kk * 4 + quad) ^ s8;
        short8 vf = *(const short8*)&lv[(nd * 16 + l16) * 64 + cc * 8];
        oh[nd] = __builtin_amdgcn_mfma_f32_16x16x32_bf16(vf, ph, oh[nd], 0, 0, 0);
        if (dlo)
          ol[nd] = __builtin_amdgcn_mfma_f32_16x16x32_bf16(vf, pl, ol[nd], 0, 0, 0);
      }
    }
  }

  // O^T regs: lane q=l16, d = nd*16 + quad*4 + r  -> 8B packed stores
  {
    float ih = 1.f / lh, il = 1.f / llo;
    size_t rh = ((size_t)b * S_LEN + qt_hi * 64 + wv * 16 + l16) * DM + head * HD;
    size_t rl = ((size_t)b * S_LEN + qt_lo * 64 + wv * 16 + l16) * DM + head * HD;
    #pragma unroll
    for (int nd = 0; nd < 8; ++nd) {
      ux4 ph, pl;
      #pragma unroll
      for (int r = 0; r < 4; ++r) {
        ph[r] = f2bf(oh[nd][r] * ih);
        pl[r] = f2bf(ol[nd][r] * il);
      }
      *(ux4*)&ctx[rh + nd * 16 + quad * 4] = ph;
      *(ux4*)&ctx[rl + nd * 16 + quad * 4] = pl;
    }
  }
}

// ---------------------------------------------------------------------------
extern "C" void kernel_launch(void* const* d_in, const int* in_sizes, int n_in,
                              void* d_out, int out_size, void* d_ws, size_t ws_size,
                              hipStream_t stream)
{
  const float* x    = (const float*)d_in[0];
  const float* Wqkv = (const float*)d_in[2];
  const float* bqkv = (const float*)d_in[3];
  const float* Wout = (const float*)d_in[4];
  const float* bout = (const float*)d_in[5];
  float* out = (float*)d_out;

  constexpr size_t XB_E = (size_t)4096 * 2048;   // 8.39M elems
  constexpr size_t WQ_E = (size_t)6144 * 2048;
  constexpr size_t WO_E = (size_t)2048 * 2048;
  constexpr size_t NEED = (XB_E + WQ_E + WO_E + 3 * XB_E) * 2;  // ~101 MB

  if (ws_size >= NEED) {
    u16* xb  = (u16*)d_ws;
    u16* wqb = xb + XB_E;
    u16* wob = wqb + WQ_E;
    u16* qb  = wob + WO_E;
    u16* kb  = qb + XB_E;
    u16* vb  = kb + XB_E;
    u16* ctx = xb;                 // xb dead after QKV GEMM; reuse for ctx

    cvt_kernel<<<dim3(XB_E / 1024), 256, 0, stream>>>(x, xb);
    cvt_kernel<<<dim3(WQ_E / 1024), 256, 0, stream>>>(Wqkv, wqb);
    cvt_kernel<<<dim3(WO_E / 1024), 256, 0, stream>>>(Wout, wob);
    gemm_bt<4096, 6144, 2048, 1, true, true><<<dim3(48, 32), 256, 0, stream>>>(
        xb, wqb, bqkv, qb, kb, vb);
    attn_kernel<<<dim3(512), 256, 0, stream>>>(qb, kb, vb, ctx);
    gemm_bt<4096, 2048, 2048, 0, true, true><<<dim3(16, 32), 256, 0, stream>>>(
        ctx, wob, bout, out, nullptr, nullptr);
  } else {
    // fallback: 48 MiB ws, fused fp32->bf16 staging in GEMMs, ctx in d_out
    u16* qb = (u16*)d_ws;
    u16* kb = qb + XB_E;
    u16* vb = kb + XB_E;
    u16* ctx = (u16*)d_out;
    float* tmpo = (float*)d_ws;   // over dead qb/kb at out-proj time

    gemm_bt<4096, 6144, 2048, 1, false, false><<<dim3(48, 32), 256, 0, stream>>>(
        x, Wqkv, bqkv, qb, kb, vb);
    attn_kernel<<<dim3(512), 256, 0, stream>>>(qb, kb, vb, ctx);
    gemm_bt<4096, 2048, 2048, 0, true, false><<<dim3(16, 32), 256, 0, stream>>>(
        ctx, Wout, bout, tmpo, nullptr, nullptr);
    hipMemcpyAsync(out, tmpo, (size_t)out_size * sizeof(float),
                   hipMemcpyDeviceToDevice, stream);
  }
}

// Round 6
// 439.618 us; speedup vs baseline: 1.1295x; 1.1295x over previous
//
#include <hip/hip_runtime.h>

typedef unsigned short u16;
typedef __attribute__((ext_vector_type(8))) short short8;
typedef __attribute__((ext_vector_type(4))) float fx4;
typedef __attribute__((ext_vector_type(4))) int ix4;
typedef __attribute__((ext_vector_type(4))) unsigned short ux4;

__device__ __forceinline__ float bf2f(u16 h) {
  union { unsigned u; float f; } a; a.u = ((unsigned)h) << 16; return a.f;
}
__device__ __forceinline__ u16 f2bf(float f) {
  union { float f; unsigned u; } a; a.f = f;
  unsigned u = a.u;
  return (u16)((u + 0x7FFFu + ((u >> 16) & 1u)) >> 16);  // RNE
}

// async global->LDS, 16B per lane. LDS dest must be wave-uniform base + lane*16.
__device__ __forceinline__ void gl_lds(const u16* g, u16* l) {
  __builtin_amdgcn_global_load_lds(
      (const __attribute__((address_space(1))) unsigned*)g,
      (__attribute__((address_space(3))) unsigned*)l, 16, 0, 0);
}

constexpr int S_LEN = 2048;
constexpr int DM = 2048;
constexpr int HD = 128;
constexpr int NH = 16;
constexpr float NEG = -1.0e9f;
constexpr float SC2 = 0.08838834764831845f * 1.4426950408889634f;  // 1/sqrt(128)*log2(e)
constexpr float INV2PI = 0.15915494309189535f;

// HW sin/cos: v_sin/v_cos take revolutions; pre-reduce with fract.
// |angle| <= 2048 rad -> 326 rev; f32 fract error ~3e-5 rev ~ 2e-4 rad,
// far below bf16 output quantization. (R5: absmax unchanged -> verified.)
__device__ __forceinline__ void fast_sincos(float rev_unred, float& sn, float& cs) {
  float rev = rev_unred - floorf(rev_unred);
  sn = __builtin_amdgcn_sinf(rev);
  cs = __builtin_amdgcn_cosf(rev);
}

// ---------------------------------------------------------------------------
// fp32 -> bf16 bulk convert, all three tensors in ONE launch (x, Wqkv, Wout).
// Block ranges: [0,8192) x, [8192,20480) Wqkv, [20480,24576) Wout.
// ---------------------------------------------------------------------------
__global__ __launch_bounds__(256)
void cvt3_kernel(const float* __restrict__ x, const float* __restrict__ wq,
                 const float* __restrict__ wo,
                 u16* __restrict__ xb, u16* __restrict__ wqb, u16* __restrict__ wob)
{
  int bid = blockIdx.x;
  const float* in; u16* out; int base;
  if (bid < 8192)       { in = x;  out = xb;  base = bid; }
  else if (bid < 20480) { in = wq; out = wqb; base = bid - 8192; }
  else                  { in = wo; out = wob; base = bid - 20480; }
  size_t idx = (size_t)base * 256 + threadIdx.x;
  fx4 v = *(const fx4*)&in[idx * 4];
  ux4 pk;
  pk[0] = f2bf(v[0]); pk[1] = f2bf(v[1]); pk[2] = f2bf(v[2]); pk[3] = f2bf(v[3]);
  *(ux4*)&out[idx * 4] = pk;
}

// ---------------------------------------------------------------------------
// GEMM: C[M,N] = A[M,K] @ W[N,K]^T + bias (bias fp32)
// MODE 0: fp32 out to o0;  MODE 1: QKV scatter bf16 (o0=Q, o1=K, o2=V^T)
//         with RoPE fused into the Q/K epilogue (HW v_sin/v_cos).
// T1 XCD swizzle: flat grid GX*32 blocks; hardware round-robins w%8 across
// XCDs, so XCD x owns n-columns [x*GX/8, (x+1)*GX/8): its W-panel
// (GX/8 * 128 * K * 2B, 3.1 MB at GX=48) stays L2-resident while A streams
// (L3-hit after first XCD). Within XCD: column-major sweep of 32 m-blocks.
// Proven 149 us / ~30% MfmaUtil structure; two phased rewrites regressed ->
// keep the 2-barrier loop, inter-block overlap does the hiding.
// ---------------------------------------------------------------------------
template<int M, int N, int K, int MODE, bool AB16, bool WB16, int GX>
__global__ __launch_bounds__(256)
void gemm_bt(const void* __restrict__ Av, const void* __restrict__ Wv,
             const float* __restrict__ bias,
             void* __restrict__ o0, u16* __restrict__ o1, u16* __restrict__ o2)
{
  constexpr int BK = 64;
  constexpr int PER = GX / 8;               // n-columns per XCD
  __shared__ u16 la[128 * BK];
  __shared__ u16 lb[128 * BK];
  const int tid  = threadIdx.x;
  const int lane = tid & 63;
  const int wv   = tid >> 6;
  const int wm   = wv >> 1, wn = wv & 1;
  const int quad = lane >> 4, l16 = lane & 15;
  const int w    = blockIdx.x;
  const int xcd  = w & 7, cid = w >> 3;
  const int n0 = (xcd * PER + cid / 32) * 128;
  const int m0 = (cid & 31) * 128;
  const int sw = l16 & 7;                     // frag-read swizzle (row&7 = l16&7)

  fx4 acc[4][4] = {};

  for (int k0 = 0; k0 < K; k0 += BK) {
    __syncthreads();
    if constexpr (AB16) {
      const u16* ap = (const u16*)Av + (size_t)m0 * K + k0;
      #pragma unroll
      for (int i = 0; i < 4; ++i) {
        int c = i * 256 + tid, row = c >> 3, cc = c & 7;
        int g = cc ^ (row & 7);
        gl_lds(ap + (size_t)row * K + g * 8, &la[c * 8]);
      }
    } else {
      const float* ap = (const float*)Av + (size_t)m0 * K + k0;
      #pragma unroll
      for (int i = 0; i < 4; ++i) {
        int c = i * 256 + tid, row = c >> 3, cc = c & 7;
        fx4 v0 = *(const fx4*)&ap[(size_t)row * K + cc * 8];
        fx4 v1 = *(const fx4*)&ap[(size_t)row * K + cc * 8 + 4];
        ux4 p0, p1;
        p0[0]=f2bf(v0[0]); p0[1]=f2bf(v0[1]); p0[2]=f2bf(v0[2]); p0[3]=f2bf(v0[3]);
        p1[0]=f2bf(v1[0]); p1[1]=f2bf(v1[1]); p1[2]=f2bf(v1[2]); p1[3]=f2bf(v1[3]);
        int s = cc ^ (row & 7);
        *(ux4*)&la[row * BK + s * 8]     = p0;
        *(ux4*)&la[row * BK + s * 8 + 4] = p1;
      }
    }
    if constexpr (WB16) {
      const u16* wp = (const u16*)Wv + (size_t)n0 * K + k0;
      #pragma unroll
      for (int i = 0; i < 4; ++i) {
        int c = i * 256 + tid, row = c >> 3, cc = c & 7;
        int g = cc ^ (row & 7);
        gl_lds(wp + (size_t)row * K + g * 8, &lb[c * 8]);
      }
    } else {
      const float* wp = (const float*)Wv + (size_t)n0 * K + k0;
      #pragma unroll
      for (int i = 0; i < 4; ++i) {
        int c = i * 256 + tid, row = c >> 3, cc = c & 7;
        fx4 v0 = *(const fx4*)&wp[(size_t)row * K + cc * 8];
        fx4 v1 = *(const fx4*)&wp[(size_t)row * K + cc * 8 + 4];
        ux4 p0, p1;
        p0[0]=f2bf(v0[0]); p0[1]=f2bf(v0[1]); p0[2]=f2bf(v0[2]); p0[3]=f2bf(v0[3]);
        p1[0]=f2bf(v1[0]); p1[1]=f2bf(v1[1]); p1[2]=f2bf(v1[2]); p1[3]=f2bf(v1[3]);
        int s = cc ^ (row & 7);
        *(ux4*)&lb[row * BK + s * 8]     = p0;
        *(ux4*)&lb[row * BK + s * 8 + 4] = p1;
      }
    }
    __syncthreads();
    #pragma unroll
    for (int ks = 0; ks < 2; ++ks) {
      short8 af[4], bfg[4];
      #pragma unroll
      for (int t = 0; t < 4; ++t) {
        int arow = wm * 64 + t * 16 + l16;
        int brow = (t & 2) * 32 + wn * 32 + (t & 1) * 16 + l16;
        int cc = (ks * 4 + quad) ^ sw;
        af[t]  = *(const short8*)&la[arow * BK + cc * 8];
        bfg[t] = *(const short8*)&lb[brow * BK + cc * 8];
      }
      #pragma unroll
      for (int mt = 0; mt < 4; ++mt)
        #pragma unroll
        for (int nt = 0; nt < 4; ++nt)
          acc[mt][nt] = __builtin_amdgcn_mfma_f32_16x16x32_bf16(af[mt], bfg[nt], acc[mt][nt], 0, 0, 0);
    }
  }

  if constexpr (MODE == 0) {
    float* of = (float*)o0;
    #pragma unroll
    for (int nt = 0; nt < 4; ++nt) {
      int col = n0 + (nt & 2) * 32 + wn * 32 + (nt & 1) * 16 + l16;
      float bz = bias[col];
      #pragma unroll
      for (int mt = 0; mt < 4; ++mt) {
        int row = m0 + wm * 64 + mt * 16 + quad * 4;
        #pragma unroll
        for (int r = 0; r < 4; ++r)
          of[(size_t)(row + r) * N + col] = acc[mt][nt][r] + bz;
      }
    }
  } else {
    const int which = n0 >> 11;
    const int head  = (n0 >> 7) & 15;
    const int b     = m0 >> 11;
    const int bh    = b * NH + head;
    if (which == 2) {
      #pragma unroll
      for (int nt = 0; nt < 4; ++nt) {
        int dcol = (nt & 2) * 32 + wn * 32 + (nt & 1) * 16 + l16;
        float bz = bias[n0 + dcol];
        #pragma unroll
        for (int mt = 0; mt < 4; ++mt) {
          int srow = (m0 & (S_LEN - 1)) + wm * 64 + mt * 16 + quad * 4;
          ux4 pk;
          #pragma unroll
          for (int r = 0; r < 4; ++r) pk[r] = f2bf(acc[mt][nt][r] + bz);
          *(ux4*)&o2[((size_t)bh * HD + dcol) * S_LEN + srow] = pk;  // V^T
        }
      }
    } else {
      // Q or K with fused RoPE: pair (i, i+64) = acc[..][nt] / acc[..][nt+2]
      u16* buf = (which == 0) ? (u16*)o0 : o1;
      #pragma unroll
      for (int nt = 0; nt < 2; ++nt) {
        int i = wn * 32 + nt * 16 + l16;            // 0..63
        // invf2 = 10000^(-i/64) / (2*pi): angle in revolutions per srow
        float invf2 = exp2f((float)i * -0.20762050594f) * INV2PI;
        float bz1 = bias[n0 + i];
        float bz2 = bias[n0 + i + 64];
        #pragma unroll
        for (int mt = 0; mt < 4; ++mt) {
          int srow = (m0 & (S_LEN - 1)) + wm * 64 + mt * 16 + quad * 4;
          size_t base = ((size_t)bh * S_LEN + srow) * HD + i;
          #pragma unroll
          for (int r = 0; r < 4; ++r) {
            float sn, cs;
            fast_sincos((float)(srow + r) * invf2, sn, cs);
            float v1 = acc[mt][nt][r] + bz1;
            float v2 = acc[mt][nt + 2][r] + bz2;
            buf[base + (size_t)r * HD]      = f2bf(v1 * cs - v2 * sn);
            buf[base + (size_t)r * HD + 64] = f2bf(v2 * cs + v1 * sn);
          }
        }
      }
    }
  }
}

// ---------------------------------------------------------------------------
// Transposed online-softmax tile step with defer-max (T13). S^T in C-layout:
// lane owns q-row=l16, 16 keys = snt*16 + quad*4 + r in registers. Row reduce
// = in-register tree + 2 shuffles. Defer the O-rescale when the tile max is
// within 8 (log2) of the running max (wave-uniform via __all).
// ---------------------------------------------------------------------------
__device__ __forceinline__ void soft_tile_t(fx4 s[4], float& m, float& l, fx4* o,
                                            u16* lp, bool mask, int qrow, int k0,
                                            int l16, int quad)
{
  #pragma unroll
  for (int snt = 0; snt < 4; ++snt)
    #pragma unroll
    for (int r = 0; r < 4; ++r) {
      float v = s[snt][r] * SC2;
      if (mask && (k0 + snt * 16 + quad * 4 + r > qrow)) v = NEG;
      s[snt][r] = v;
    }
  float mx = s[0][0];
  #pragma unroll
  for (int snt = 0; snt < 4; ++snt)
    #pragma unroll
    for (int r = 0; r < 4; ++r) mx = fmaxf(mx, s[snt][r]);
  mx = fmaxf(mx, __shfl_xor(mx, 16, 64));
  mx = fmaxf(mx, __shfl_xor(mx, 32, 64));

  const bool defer = __all(mx <= m + 8.f);   // wave-uniform
  float al = 1.f;
  if (!defer) {
    float mn = fmaxf(m, mx);
    al = exp2f(m - mn);
    m = mn;
  }
  float rs = 0.f;
  #pragma unroll
  for (int snt = 0; snt < 4; ++snt)
    #pragma unroll
    for (int r = 0; r < 4; ++r) {
      float pz = exp2f(s[snt][r] - m);
      s[snt][r] = pz;
      rs += pz;
    }
  rs += __shfl_xor(rs, 16, 64);
  rs += __shfl_xor(rs, 32, 64);
  l = l * al + rs;
  if (!defer) {
    #pragma unroll
    for (int nd = 0; nd < 8; ++nd)
      #pragma unroll
      for (int r = 0; r < 4; ++r) o[nd][r] *= al;
  }
  #pragma unroll
  for (int snt = 0; snt < 4; ++snt) {
    ux4 pk;
    #pragma unroll
    for (int r = 0; r < 4; ++r) pk[r] = f2bf(s[snt][r]);
    *(ux4*)&lp[l16 * 72 + snt * 16 + quad * 4] = pk;   // 8B write
  }
}

// ---------------------------------------------------------------------------
// Flash attention (causal), UNPAIRED q-tiles (R4-proven config), transposed
// pipeline: S^T = K·Q^T and O^T = V^T·P^T. Per-lane-scalar softmax.
// Grid: flat 1024; w%8 = XCD (confirmed: FETCH 144->36 MB in R5), each XCD
// owns 4 bh (4 MB K/V = one L2). LPT: qt = 31-((w>>3)&31) launches heavy
// blocks first, trimming the tail that capped occupancy.
// LDS: K 16K + V^T 16K + per-wave P 9K = 41 KB -> 3 blocks/CU = 12 waves/CU;
// inter-block TLP hides the stage drain + serial softmax chain (pairing at
// 512 blocks = 2/CU measured 40 us WORSE -> keep 1024 blocks).
// ---------------------------------------------------------------------------
__global__ __launch_bounds__(256, 3)
void attn_kernel(const u16* __restrict__ qbuf, const u16* __restrict__ kbuf,
                 const u16* __restrict__ vtbuf, u16* __restrict__ ctx)
{
  __shared__ u16 lk[64 * 128];     // K tile  [key][d],  swizzled chunks
  __shared__ u16 lv[128 * 64];     // V^T tile [d][key], swizzled chunks
  __shared__ u16 lp[4][16 * 72];   // per-wave P [q][key]
  const int tid = threadIdx.x, lane = tid & 63, wv = tid >> 6;
  const int quad = lane >> 4, l16 = lane & 15;
  const int w = blockIdx.x;
  const int bh = (w & 7) * 4 + ((w >> 3) >> 5);   // XCD-grouped head
  const int qt = 31 - ((w >> 3) & 31);            // q-tile, heavy first (LPT)
  const int head = bh & 15, b = bh >> 4;
  const int s8 = l16 & 7;          // frag-read swizzle index

  short8 qh[4];
  {
    const size_t q_ = ((size_t)bh * S_LEN + qt * 64 + wv * 16 + l16) * HD;
    #pragma unroll
    for (int kd = 0; kd < 4; ++kd)
      qh[kd] = *(const short8*)&qbuf[q_ + kd * 32 + quad * 8];
  }

  fx4 oh[8] = {};
  float m = NEG, l = 0.f;
  const int qrow = qt * 64 + wv * 16 + l16;

  for (int kt = 0; kt <= qt; ++kt) {
    if (kt) __syncthreads();                 // WAR vs previous compute
    {
      const u16* kg = kbuf + ((size_t)bh * S_LEN + kt * 64) * HD;
      const u16* vg = vtbuf + (size_t)bh * HD * S_LEN + kt * 64;
      #pragma unroll
      for (int i = 0; i < 4; ++i) {          // K tile: 64 rows x 16 chunks
        int c = i * 256 + tid;
        int row = c >> 4, cc = c & 15;
        int g = cc ^ (row & 7);
        gl_lds(kg + (size_t)row * HD + g * 8, &lk[c * 8]);
      }
      #pragma unroll
      for (int i = 0; i < 4; ++i) {          // V^T tile: 128 rows x 8 chunks
        int c = i * 256 + tid;
        int row = c >> 3, cc = c & 7;
        int g = cc ^ (row & 7);
        gl_lds(vg + (size_t)row * S_LEN + g * 8, &lv[c * 8]);
      }
    }
    __syncthreads();                         // RAW: drain stage

    // S^T = K·Q^T
    fx4 sh[4] = {};
    #pragma unroll
    for (int snt = 0; snt < 4; ++snt) {
      #pragma unroll
      for (int kd = 0; kd < 4; ++kd) {
        int cc = (kd * 4 + quad) ^ s8;
        short8 kf = *(const short8*)&lk[(snt * 16 + l16) * 128 + cc * 8];
        sh[snt] = __builtin_amdgcn_mfma_f32_16x16x32_bf16(kf, qh[kd], sh[snt], 0, 0, 0);
      }
    }

    soft_tile_t(sh, m, l, oh, lp[wv], kt == qt, qrow, kt * 64, l16, quad);

    // O^T += V^T·P^T
    #pragma unroll
    for (int kk = 0; kk < 2; ++kk) {
      short8 ph = *(const short8*)&lp[wv][l16 * 72 + kk * 32 + quad * 8];
      #pragma unroll
      for (int nd = 0; nd < 8; ++nd) {
        int cc = (kk * 4 + quad) ^ s8;
        short8 vf = *(const short8*)&lv[(nd * 16 + l16) * 64 + cc * 8];
        oh[nd] = __builtin_amdgcn_mfma_f32_16x16x32_bf16(vf, ph, oh[nd], 0, 0, 0);
      }
    }
  }

  // O^T regs: lane q=l16, d = nd*16 + quad*4 + r  -> 8B packed stores
  {
    float ih = 1.f / l;
    size_t rh = ((size_t)b * S_LEN + qt * 64 + wv * 16 + l16) * DM + head * HD;
    #pragma unroll
    for (int nd = 0; nd < 8; ++nd) {
      ux4 ph;
      #pragma unroll
      for (int r = 0; r < 4; ++r) ph[r] = f2bf(oh[nd][r] * ih);
      *(ux4*)&ctx[rh + nd * 16 + quad * 4] = ph;
    }
  }
}

// ---------------------------------------------------------------------------
extern "C" void kernel_launch(void* const* d_in, const int* in_sizes, int n_in,
                              void* d_out, int out_size, void* d_ws, size_t ws_size,
                              hipStream_t stream)
{
  const float* x    = (const float*)d_in[0];
  const float* Wqkv = (const float*)d_in[2];
  const float* bqkv = (const float*)d_in[3];
  const float* Wout = (const float*)d_in[4];
  const float* bout = (const float*)d_in[5];
  float* out = (float*)d_out;

  constexpr size_t XB_E = (size_t)4096 * 2048;   // 8.39M elems
  constexpr size_t WQ_E = (size_t)6144 * 2048;
  constexpr size_t WO_E = (size_t)2048 * 2048;
  constexpr size_t NEED = (XB_E + WQ_E + WO_E + 3 * XB_E) * 2;  // ~101 MB

  if (ws_size >= NEED) {
    u16* xb  = (u16*)d_ws;
    u16* wqb = xb + XB_E;
    u16* wob = wqb + WQ_E;
    u16* qb  = wob + WO_E;
    u16* kb  = qb + XB_E;
    u16* vb  = kb + XB_E;
    u16* ctx = xb;                 // xb dead after QKV GEMM; reuse for ctx

    cvt3_kernel<<<dim3(24576), 256, 0, stream>>>(x, Wqkv, Wout, xb, wqb, wob);
    gemm_bt<4096, 6144, 2048, 1, true, true, 48><<<dim3(1536), 256, 0, stream>>>(
        xb, wqb, bqkv, qb, kb, vb);
    attn_kernel<<<dim3(1024), 256, 0, stream>>>(qb, kb, vb, ctx);
    gemm_bt<4096, 2048, 2048, 0, true, true, 16><<<dim3(512), 256, 0, stream>>>(
        ctx, wob, bout, out, nullptr, nullptr);
  } else {
    // fallback: 48 MiB ws, fused fp32->bf16 staging in GEMMs, ctx in d_out
    u16* qb = (u16*)d_ws;
    u16* kb = qb + XB_E;
    u16* vb = kb + XB_E;
    u16* ctx = (u16*)d_out;
    float* tmpo = (float*)d_ws;   // over dead qb/kb at out-proj time

    gemm_bt<4096, 6144, 2048, 1, false, false, 48><<<dim3(1536), 256, 0, stream>>>(
        x, Wqkv, bqkv, qb, kb, vb);
    attn_kernel<<<dim3(1024), 256, 0, stream>>>(qb, kb, vb, ctx);
    gemm_bt<4096, 2048, 2048, 0, true, false, 16><<<dim3(512), 256, 0, stream>>>(
        ctx, Wout, bout, tmpo, nullptr, nullptr);
    hipMemcpyAsync(out, tmpo, (size_t)out_size * sizeof(float),
                   hipMemcpyDeviceToDevice, stream);
  }
}

// Round 7
// 432.578 us; speedup vs baseline: 1.1479x; 1.0163x over previous
//
#include <hip/hip_runtime.h>

typedef unsigned short u16;
typedef __attribute__((ext_vector_type(8))) short short8;
typedef __attribute__((ext_vector_type(4))) float fx4;
typedef __attribute__((ext_vector_type(4))) int ix4;
typedef __attribute__((ext_vector_type(4))) unsigned short ux4;

__device__ __forceinline__ float bf2f(u16 h) {
  union { unsigned u; float f; } a; a.u = ((unsigned)h) << 16; return a.f;
}
__device__ __forceinline__ u16 f2bf(float f) {
  union { float f; unsigned u; } a; a.f = f;
  unsigned u = a.u;
  return (u16)((u + 0x7FFFu + ((u >> 16) & 1u)) >> 16);  // RNE
}

// async global->LDS, 16B per lane. LDS dest must be wave-uniform base + lane*16.
__device__ __forceinline__ void gl_lds(const u16* g, u16* l) {
  __builtin_amdgcn_global_load_lds(
      (const __attribute__((address_space(1))) unsigned*)g,
      (__attribute__((address_space(3))) unsigned*)l, 16, 0, 0);
}

constexpr int S_LEN = 2048;
constexpr int DM = 2048;
constexpr int HD = 128;
constexpr int NH = 16;
constexpr float NEG = -1.0e9f;
constexpr float SC2 = 0.08838834764831845f * 1.4426950408889634f;  // 1/sqrt(128)*log2(e)
constexpr float INV2PI = 0.15915494309189535f;

// HW sin/cos: v_sin/v_cos take revolutions; pre-reduce with fract.
// |angle| <= 2048 rad -> 326 rev; f32 fract error ~3e-5 rev ~ 2e-4 rad,
// far below bf16 output quantization. (R5/R6: absmax unchanged -> verified.)
__device__ __forceinline__ void fast_sincos(float rev_unred, float& sn, float& cs) {
  float rev = rev_unred - floorf(rev_unred);
  sn = __builtin_amdgcn_sinf(rev);
  cs = __builtin_amdgcn_cosf(rev);
}

// ---------------------------------------------------------------------------
// fp32 -> bf16 bulk convert, all three tensors in ONE launch (x, Wqkv, Wout).
// ---------------------------------------------------------------------------
__global__ __launch_bounds__(256)
void cvt3_kernel(const float* __restrict__ x, const float* __restrict__ wq,
                 const float* __restrict__ wo,
                 u16* __restrict__ xb, u16* __restrict__ wqb, u16* __restrict__ wob)
{
  int bid = blockIdx.x;
  const float* in; u16* out; int base;
  if (bid < 8192)       { in = x;  out = xb;  base = bid; }
  else if (bid < 20480) { in = wq; out = wqb; base = bid - 8192; }
  else                  { in = wo; out = wob; base = bid - 20480; }
  size_t idx = (size_t)base * 256 + threadIdx.x;
  fx4 v = *(const fx4*)&in[idx * 4];
  ux4 pk;
  pk[0] = f2bf(v[0]); pk[1] = f2bf(v[1]); pk[2] = f2bf(v[2]); pk[3] = f2bf(v[3]);
  *(ux4*)&out[idx * 4] = pk;
}

// ---------------------------------------------------------------------------
// GEMM: C[M,N] = A[M,K] @ W[N,K]^T + bias (bias fp32)
// MODE 0: fp32 out to o0;  MODE 1: QKV scatter bf16 (o0=Q, o1=K, o2=V^T)
//         with RoPE fused into the Q/K epilogue (HW v_sin/v_cos).
// 2D grid (n fastest): concurrently-dispatched blocks share one A-panel
// (512 KB) + few W-panels per XCD L2 -- measured best (R6's "XCD owns an
// n-column" swizzle DOUBLED fetch: it destroyed A-panel sharing). Keep the
// proven 2-barrier loop; phased rewrites regressed twice.
// ---------------------------------------------------------------------------
template<int M, int N, int K, int MODE, bool AB16, bool WB16>
__global__ __launch_bounds__(256)
void gemm_bt(const void* __restrict__ Av, const void* __restrict__ Wv,
             const float* __restrict__ bias,
             void* __restrict__ o0, u16* __restrict__ o1, u16* __restrict__ o2)
{
  constexpr int BK = 64;
  __shared__ u16 la[128 * BK];
  __shared__ u16 lb[128 * BK];
  const int tid  = threadIdx.x;
  const int lane = tid & 63;
  const int wv   = tid >> 6;
  const int wm   = wv >> 1, wn = wv & 1;
  const int quad = lane >> 4, l16 = lane & 15;
  const int m0 = blockIdx.y * 128, n0 = blockIdx.x * 128;
  const int sw = l16 & 7;                     // frag-read swizzle (row&7 = l16&7)

  fx4 acc[4][4] = {};

  for (int k0 = 0; k0 < K; k0 += BK) {
    __syncthreads();
    if constexpr (AB16) {
      const u16* ap = (const u16*)Av + (size_t)m0 * K + k0;
      #pragma unroll
      for (int i = 0; i < 4; ++i) {
        int c = i * 256 + tid, row = c >> 3, cc = c & 7;
        int g = cc ^ (row & 7);
        gl_lds(ap + (size_t)row * K + g * 8, &la[c * 8]);
      }
    } else {
      const float* ap = (const float*)Av + (size_t)m0 * K + k0;
      #pragma unroll
      for (int i = 0; i < 4; ++i) {
        int c = i * 256 + tid, row = c >> 3, cc = c & 7;
        fx4 v0 = *(const fx4*)&ap[(size_t)row * K + cc * 8];
        fx4 v1 = *(const fx4*)&ap[(size_t)row * K + cc * 8 + 4];
        ux4 p0, p1;
        p0[0]=f2bf(v0[0]); p0[1]=f2bf(v0[1]); p0[2]=f2bf(v0[2]); p0[3]=f2bf(v0[3]);
        p1[0]=f2bf(v1[0]); p1[1]=f2bf(v1[1]); p1[2]=f2bf(v1[2]); p1[3]=f2bf(v1[3]);
        int s = cc ^ (row & 7);
        *(ux4*)&la[row * BK + s * 8]     = p0;
        *(ux4*)&la[row * BK + s * 8 + 4] = p1;
      }
    }
    if constexpr (WB16) {
      const u16* wp = (const u16*)Wv + (size_t)n0 * K + k0;
      #pragma unroll
      for (int i = 0; i < 4; ++i) {
        int c = i * 256 + tid, row = c >> 3, cc = c & 7;
        int g = cc ^ (row & 7);
        gl_lds(wp + (size_t)row * K + g * 8, &lb[c * 8]);
      }
    } else {
      const float* wp = (const float*)Wv + (size_t)n0 * K + k0;
      #pragma unroll
      for (int i = 0; i < 4; ++i) {
        int c = i * 256 + tid, row = c >> 3, cc = c & 7;
        fx4 v0 = *(const fx4*)&wp[(size_t)row * K + cc * 8];
        fx4 v1 = *(const fx4*)&wp[(size_t)row * K + cc * 8 + 4];
        ux4 p0, p1;
        p0[0]=f2bf(v0[0]); p0[1]=f2bf(v0[1]); p0[2]=f2bf(v0[2]); p0[3]=f2bf(v0[3]);
        p1[0]=f2bf(v1[0]); p1[1]=f2bf(v1[1]); p1[2]=f2bf(v1[2]); p1[3]=f2bf(v1[3]);
        int s = cc ^ (row & 7);
        *(ux4*)&lb[row * BK + s * 8]     = p0;
        *(ux4*)&lb[row * BK + s * 8 + 4] = p1;
      }
    }
    __syncthreads();
    #pragma unroll
    for (int ks = 0; ks < 2; ++ks) {
      short8 af[4], bfg[4];
      #pragma unroll
      for (int t = 0; t < 4; ++t) {
        int arow = wm * 64 + t * 16 + l16;
        int brow = (t & 2) * 32 + wn * 32 + (t & 1) * 16 + l16;
        int cc = (ks * 4 + quad) ^ sw;
        af[t]  = *(const short8*)&la[arow * BK + cc * 8];
        bfg[t] = *(const short8*)&lb[brow * BK + cc * 8];
      }
      #pragma unroll
      for (int mt = 0; mt < 4; ++mt)
        #pragma unroll
        for (int nt = 0; nt < 4; ++nt)
          acc[mt][nt] = __builtin_amdgcn_mfma_f32_16x16x32_bf16(af[mt], bfg[nt], acc[mt][nt], 0, 0, 0);
    }
  }

  if constexpr (MODE == 0) {
    float* of = (float*)o0;
    #pragma unroll
    for (int nt = 0; nt < 4; ++nt) {
      int col = n0 + (nt & 2) * 32 + wn * 32 + (nt & 1) * 16 + l16;
      float bz = bias[col];
      #pragma unroll
      for (int mt = 0; mt < 4; ++mt) {
        int row = m0 + wm * 64 + mt * 16 + quad * 4;
        #pragma unroll
        for (int r = 0; r < 4; ++r)
          of[(size_t)(row + r) * N + col] = acc[mt][nt][r] + bz;
      }
    }
  } else {
    const int which = n0 >> 11;
    const int head  = (n0 >> 7) & 15;
    const int b     = m0 >> 11;
    const int bh    = b * NH + head;
    if (which == 2) {
      #pragma unroll
      for (int nt = 0; nt < 4; ++nt) {
        int dcol = (nt & 2) * 32 + wn * 32 + (nt & 1) * 16 + l16;
        float bz = bias[n0 + dcol];
        #pragma unroll
        for (int mt = 0; mt < 4; ++mt) {
          int srow = (m0 & (S_LEN - 1)) + wm * 64 + mt * 16 + quad * 4;
          ux4 pk;
          #pragma unroll
          for (int r = 0; r < 4; ++r) pk[r] = f2bf(acc[mt][nt][r] + bz);
          *(ux4*)&o2[((size_t)bh * HD + dcol) * S_LEN + srow] = pk;  // V^T
        }
      }
    } else {
      // Q or K with fused RoPE: pair (i, i+64) = acc[..][nt] / acc[..][nt+2]
      u16* buf = (which == 0) ? (u16*)o0 : o1;
      #pragma unroll
      for (int nt = 0; nt < 2; ++nt) {
        int i = wn * 32 + nt * 16 + l16;            // 0..63
        // invf2 = 10000^(-i/64) / (2*pi): angle in revolutions per srow
        float invf2 = exp2f((float)i * -0.20762050594f) * INV2PI;
        float bz1 = bias[n0 + i];
        float bz2 = bias[n0 + i + 64];
        #pragma unroll
        for (int mt = 0; mt < 4; ++mt) {
          int srow = (m0 & (S_LEN - 1)) + wm * 64 + mt * 16 + quad * 4;
          size_t base = ((size_t)bh * S_LEN + srow) * HD + i;
          #pragma unroll
          for (int r = 0; r < 4; ++r) {
            float sn, cs;
            fast_sincos((float)(srow + r) * invf2, sn, cs);
            float v1 = acc[mt][nt][r] + bz1;
            float v2 = acc[mt][nt + 2][r] + bz2;
            buf[base + (size_t)r * HD]      = f2bf(v1 * cs - v2 * sn);
            buf[base + (size_t)r * HD + 64] = f2bf(v2 * cs + v1 * sn);
          }
        }
      }
    }
  }
}

// ---------------------------------------------------------------------------
// Transposed online-softmax tile step with defer-max (T13). S^T in C-layout:
// lane owns q-row=l16, 16 keys = snt*16 + quad*4 + r in registers. Row reduce
// = in-register tree + 2 shuffles. Defer the O-rescale when the tile max is
// within 8 (log2) of the running max (wave-uniform via __all).
// P row = 64 u16 exactly (LDS budget); bank spread via in-row XOR swizzle
// off ^= (l16&7)<<3 -- same-lane write/read, so the bijection is consistent;
// banks: (snt*8+quad*2)^((l16&7)*4) -> 2 lanes/bank = conflict-free.
// ---------------------------------------------------------------------------
__device__ __forceinline__ void soft_tile_t(fx4 s[4], float& m, float& l, fx4* o,
                                            u16* lp, bool mask, int qrow, int k0,
                                            int l16, int quad)
{
  #pragma unroll
  for (int snt = 0; snt < 4; ++snt)
    #pragma unroll
    for (int r = 0; r < 4; ++r) {
      float v = s[snt][r] * SC2;
      if (mask && (k0 + snt * 16 + quad * 4 + r > qrow)) v = NEG;
      s[snt][r] = v;
    }
  float mx = s[0][0];
  #pragma unroll
  for (int snt = 0; snt < 4; ++snt)
    #pragma unroll
    for (int r = 0; r < 4; ++r) mx = fmaxf(mx, s[snt][r]);
  mx = fmaxf(mx, __shfl_xor(mx, 16, 64));
  mx = fmaxf(mx, __shfl_xor(mx, 32, 64));

  const bool defer = __all(mx <= m + 8.f);   // wave-uniform
  float al = 1.f;
  if (!defer) {
    float mn = fmaxf(m, mx);
    al = exp2f(m - mn);
    m = mn;
  }
  float rs = 0.f;
  #pragma unroll
  for (int snt = 0; snt < 4; ++snt)
    #pragma unroll
    for (int r = 0; r < 4; ++r) {
      float pz = exp2f(s[snt][r] - m);
      s[snt][r] = pz;
      rs += pz;
    }
  rs += __shfl_xor(rs, 16, 64);
  rs += __shfl_xor(rs, 32, 64);
  l = l * al + rs;
  if (!defer) {
    #pragma unroll
    for (int nd = 0; nd < 8; ++nd)
      #pragma unroll
      for (int r = 0; r < 4; ++r) o[nd][r] *= al;
  }
  const int psw = (l16 & 7) << 3;
  #pragma unroll
  for (int snt = 0; snt < 4; ++snt) {
    ux4 pk;
    #pragma unroll
    for (int r = 0; r < 4; ++r) pk[r] = f2bf(s[snt][r]);
    *(ux4*)&lp[l16 * 64 + ((snt * 16 + quad * 4) ^ psw)] = pk;   // 8B write
  }
}

// ---------------------------------------------------------------------------
// Flash attention (causal), UNPAIRED q-tiles, transposed pipeline:
// S^T = K·Q^T and O^T = V^T·P^T. Per-lane-scalar softmax.
// Grid: flat 1024; w%8 = XCD (confirmed FETCH 144->36 MB), each XCD owns
// 4 bh (4 MB K/V = one L2). LPT: qt = 31-((w>>3)&31).
// LDS: K 16K + V^T 16K + per-wave P 8K = 40960 B exactly -> 4 blocks/CU
// (4 x 40960 = 163840 = full LDS pool) = 16 waves/CU; the whole 1024-block
// grid is resident at once (zero dispatch tail). Inter-block TLP is the
// proven hiding mechanism for the stage drain + serial softmax chain.
// ---------------------------------------------------------------------------
__global__ __launch_bounds__(256, 4)
void attn_kernel(const u16* __restrict__ qbuf, const u16* __restrict__ kbuf,
                 const u16* __restrict__ vtbuf, u16* __restrict__ ctx)
{
  __shared__ u16 lk[64 * 128];     // K tile  [key][d],  swizzled chunks (16 KiB)
  __shared__ u16 lv[128 * 64];     // V^T tile [d][key], swizzled chunks (16 KiB)
  __shared__ u16 lp[4][16 * 64];   // per-wave P [q][key], in-row XOR (8 KiB)
  const int tid = threadIdx.x, lane = tid & 63, wv = tid >> 6;
  const int quad = lane >> 4, l16 = lane & 15;
  const int w = blockIdx.x;
  const int bh = (w & 7) * 4 + ((w >> 3) >> 5);   // XCD-grouped head
  const int qt = 31 - ((w >> 3) & 31);            // q-tile, heavy first (LPT)
  const int head = bh & 15, b = bh >> 4;
  const int s8 = l16 & 7;          // frag-read swizzle index

  short8 qh[4];
  {
    const size_t q_ = ((size_t)bh * S_LEN + qt * 64 + wv * 16 + l16) * HD;
    #pragma unroll
    for (int kd = 0; kd < 4; ++kd)
      qh[kd] = *(const short8*)&qbuf[q_ + kd * 32 + quad * 8];
  }

  fx4 oh[8] = {};
  float m = NEG, l = 0.f;
  const int qrow = qt * 64 + wv * 16 + l16;
  const int psw = s8 << 3;         // P-row XOR swizzle

  for (int kt = 0; kt <= qt; ++kt) {
    if (kt) __syncthreads();                 // WAR vs previous compute
    {
      const u16* kg = kbuf + ((size_t)bh * S_LEN + kt * 64) * HD;
      const u16* vg = vtbuf + (size_t)bh * HD * S_LEN + kt * 64;
      #pragma unroll
      for (int i = 0; i < 4; ++i) {          // K tile: 64 rows x 16 chunks
        int c = i * 256 + tid;
        int row = c >> 4, cc = c & 15;
        int g = cc ^ (row & 7);
        gl_lds(kg + (size_t)row * HD + g * 8, &lk[c * 8]);
      }
      #pragma unroll
      for (int i = 0; i < 4; ++i) {          // V^T tile: 128 rows x 8 chunks
        int c = i * 256 + tid;
        int row = c >> 3, cc = c & 7;
        int g = cc ^ (row & 7);
        gl_lds(vg + (size_t)row * S_LEN + g * 8, &lv[c * 8]);
      }
    }
    __syncthreads();                         // RAW: drain stage

    // S^T = K·Q^T
    fx4 sh[4] = {};
    #pragma unroll
    for (int snt = 0; snt < 4; ++snt) {
      #pragma unroll
      for (int kd = 0; kd < 4; ++kd) {
        int cc = (kd * 4 + quad) ^ s8;
        short8 kf = *(const short8*)&lk[(snt * 16 + l16) * 128 + cc * 8];
        sh[snt] = __builtin_amdgcn_mfma_f32_16x16x32_bf16(kf, qh[kd], sh[snt], 0, 0, 0);
      }
    }

    soft_tile_t(sh, m, l, oh, lp[wv], kt == qt, qrow, kt * 64, l16, quad);

    // O^T += V^T·P^T
    #pragma unroll
    for (int kk = 0; kk < 2; ++kk) {
      short8 ph = *(const short8*)&lp[wv][l16 * 64 + ((kk * 32 + quad * 8) ^ psw)];
      #pragma unroll
      for (int nd = 0; nd < 8; ++nd) {
        int cc = (kk * 4 + quad) ^ s8;
        short8 vf = *(const short8*)&lv[(nd * 16 + l16) * 64 + cc * 8];
        oh[nd] = __builtin_amdgcn_mfma_f32_16x16x32_bf16(vf, ph, oh[nd], 0, 0, 0);
      }
    }
  }

  // O^T regs: lane q=l16, d = nd*16 + quad*4 + r  -> 8B packed stores
  {
    float ih = 1.f / l;
    size_t rh = ((size_t)b * S_LEN + qt * 64 + wv * 16 + l16) * DM + head * HD;
    #pragma unroll
    for (int nd = 0; nd < 8; ++nd) {
      ux4 ph;
      #pragma unroll
      for (int r = 0; r < 4; ++r) ph[r] = f2bf(oh[nd][r] * ih);
      *(ux4*)&ctx[rh + nd * 16 + quad * 4] = ph;
    }
  }
}

// ---------------------------------------------------------------------------
extern "C" void kernel_launch(void* const* d_in, const int* in_sizes, int n_in,
                              void* d_out, int out_size, void* d_ws, size_t ws_size,
                              hipStream_t stream)
{
  const float* x    = (const float*)d_in[0];
  const float* Wqkv = (const float*)d_in[2];
  const float* bqkv = (const float*)d_in[3];
  const float* Wout = (const float*)d_in[4];
  const float* bout = (const float*)d_in[5];
  float* out = (float*)d_out;

  constexpr size_t XB_E = (size_t)4096 * 2048;   // 8.39M elems
  constexpr size_t WQ_E = (size_t)6144 * 2048;
  constexpr size_t WO_E = (size_t)2048 * 2048;
  constexpr size_t NEED = (XB_E + WQ_E + WO_E + 3 * XB_E) * 2;  // ~101 MB

  if (ws_size >= NEED) {
    u16* xb  = (u16*)d_ws;
    u16* wqb = xb + XB_E;
    u16* wob = wqb + WQ_E;
    u16* qb  = wob + WO_E;
    u16* kb  = qb + XB_E;
    u16* vb  = kb + XB_E;
    u16* ctx = xb;                 // xb dead after QKV GEMM; reuse for ctx

    cvt3_kernel<<<dim3(24576), 256, 0, stream>>>(x, Wqkv, Wout, xb, wqb, wob);
    gemm_bt<4096, 6144, 2048, 1, true, true><<<dim3(48, 32), 256, 0, stream>>>(
        xb, wqb, bqkv, qb, kb, vb);
    attn_kernel<<<dim3(1024), 256, 0, stream>>>(qb, kb, vb, ctx);
    gemm_bt<4096, 2048, 2048, 0, true, true><<<dim3(16, 32), 256, 0, stream>>>(
        ctx, wob, bout, out, nullptr, nullptr);
  } else {
    // fallback: 48 MiB ws, fused fp32->bf16 staging in GEMMs, ctx in d_out
    u16* qb = (u16*)d_ws;
    u16* kb = qb + XB_E;
    u16* vb = kb + XB_E;
    u16* ctx = (u16*)d_out;
    float* tmpo = (float*)d_ws;   // over dead qb/kb at out-proj time

    gemm_bt<4096, 6144, 2048, 1, false, false><<<dim3(48, 32), 256, 0, stream>>>(
        x, Wqkv, bqkv, qb, kb, vb);
    attn_kernel<<<dim3(1024), 256, 0, stream>>>(qb, kb, vb, ctx);
    gemm_bt<4096, 2048, 2048, 0, true, false><<<dim3(16, 32), 256, 0, stream>>>(
        ctx, Wout, bout, tmpo, nullptr, nullptr);
    hipMemcpyAsync(out, tmpo, (size_t)out_size * sizeof(float),
                   hipMemcpyDeviceToDevice, stream);
  }
}

// Round 8
// 406.392 us; speedup vs baseline: 1.2219x; 1.0644x over previous
//
#include <hip/hip_runtime.h>

typedef unsigned short u16;
typedef __attribute__((ext_vector_type(8))) short short8;
typedef __attribute__((ext_vector_type(4))) float fx4;
typedef __attribute__((ext_vector_type(4))) int ix4;
typedef __attribute__((ext_vector_type(4))) unsigned short ux4;

__device__ __forceinline__ float bf2f(u16 h) {
  union { unsigned u; float f; } a; a.u = ((unsigned)h) << 16; return a.f;
}
__device__ __forceinline__ u16 f2bf(float f) {
  union { float f; unsigned u; } a; a.f = f;
  unsigned u = a.u;
  return (u16)((u + 0x7FFFu + ((u >> 16) & 1u)) >> 16);  // RNE
}

// async global->LDS, 16B per lane. LDS dest must be wave-uniform base + lane*16.
__device__ __forceinline__ void gl_lds(const u16* g, u16* l) {
  __builtin_amdgcn_global_load_lds(
      (const __attribute__((address_space(1))) unsigned*)g,
      (__attribute__((address_space(3))) unsigned*)l, 16, 0, 0);
}

constexpr int S_LEN = 2048;
constexpr int DM = 2048;
constexpr int HD = 128;
constexpr int NH = 16;
constexpr float NEG = -1.0e9f;
constexpr float SC2 = 0.08838834764831845f * 1.4426950408889634f;  // 1/sqrt(128)*log2(e)
constexpr float INV2PI = 0.15915494309189535f;

// HW sin/cos: v_sin/v_cos take revolutions; pre-reduce with fract.
// |angle| <= 2048 rad -> 326 rev; f32 fract error ~3e-5 rev ~ 2e-4 rad,
// far below bf16 output quantization. (R5-R7: absmax unchanged -> verified.)
__device__ __forceinline__ void fast_sincos(float rev_unred, float& sn, float& cs) {
  float rev = rev_unred - floorf(rev_unred);
  sn = __builtin_amdgcn_sinf(rev);
  cs = __builtin_amdgcn_cosf(rev);
}

// ---------------------------------------------------------------------------
// fp32 -> bf16 bulk convert, all three tensors in ONE launch (x, Wqkv, Wout).
// ---------------------------------------------------------------------------
__global__ __launch_bounds__(256)
void cvt3_kernel(const float* __restrict__ x, const float* __restrict__ wq,
                 const float* __restrict__ wo,
                 u16* __restrict__ xb, u16* __restrict__ wqb, u16* __restrict__ wob)
{
  int bid = blockIdx.x;
  const float* in; u16* out; int base;
  if (bid < 8192)       { in = x;  out = xb;  base = bid; }
  else if (bid < 20480) { in = wq; out = wqb; base = bid - 8192; }
  else                  { in = wo; out = wob; base = bid - 20480; }
  size_t idx = (size_t)base * 256 + threadIdx.x;
  fx4 v = *(const fx4*)&in[idx * 4];
  ux4 pk;
  pk[0] = f2bf(v[0]); pk[1] = f2bf(v[1]); pk[2] = f2bf(v[2]); pk[3] = f2bf(v[3]);
  *(ux4*)&out[idx * 4] = pk;
}

// ---------------------------------------------------------------------------
// GEMM: C[M,N] = A[M,K] @ W[N,K]^T + bias (bias fp32)
// MODE 0: fp32 out to o0;  MODE 1: QKV scatter bf16 (o0=Q, o1=K, o2=V^T)
//         with RoPE fused into the Q/K epilogue (HW v_sin/v_cos).
// 2D grid (n fastest): concurrent blocks share one A-panel + few W-panels in
// each XCD L2 -- measured best (R6's XCD column-ownership DOUBLED fetch).
// Keep the proven 2-barrier loop; phased rewrites regressed twice.
// ---------------------------------------------------------------------------
template<int M, int N, int K, int MODE, bool AB16, bool WB16>
__global__ __launch_bounds__(256)
void gemm_bt(const void* __restrict__ Av, const void* __restrict__ Wv,
             const float* __restrict__ bias,
             void* __restrict__ o0, u16* __restrict__ o1, u16* __restrict__ o2)
{
  constexpr int BK = 64;
  __shared__ u16 la[128 * BK];
  __shared__ u16 lb[128 * BK];
  const int tid  = threadIdx.x;
  const int lane = tid & 63;
  const int wv   = tid >> 6;
  const int wm   = wv >> 1, wn = wv & 1;
  const int quad = lane >> 4, l16 = lane & 15;
  const int m0 = blockIdx.y * 128, n0 = blockIdx.x * 128;
  const int sw = l16 & 7;                     // frag-read swizzle (row&7 = l16&7)

  fx4 acc[4][4] = {};

  for (int k0 = 0; k0 < K; k0 += BK) {
    __syncthreads();
    if constexpr (AB16) {
      const u16* ap = (const u16*)Av + (size_t)m0 * K + k0;
      #pragma unroll
      for (int i = 0; i < 4; ++i) {
        int c = i * 256 + tid, row = c >> 3, cc = c & 7;
        int g = cc ^ (row & 7);
        gl_lds(ap + (size_t)row * K + g * 8, &la[c * 8]);
      }
    } else {
      const float* ap = (const float*)Av + (size_t)m0 * K + k0;
      #pragma unroll
      for (int i = 0; i < 4; ++i) {
        int c = i * 256 + tid, row = c >> 3, cc = c & 7;
        fx4 v0 = *(const fx4*)&ap[(size_t)row * K + cc * 8];
        fx4 v1 = *(const fx4*)&ap[(size_t)row * K + cc * 8 + 4];
        ux4 p0, p1;
        p0[0]=f2bf(v0[0]); p0[1]=f2bf(v0[1]); p0[2]=f2bf(v0[2]); p0[3]=f2bf(v0[3]);
        p1[0]=f2bf(v1[0]); p1[1]=f2bf(v1[1]); p1[2]=f2bf(v1[2]); p1[3]=f2bf(v1[3]);
        int s = cc ^ (row & 7);
        *(ux4*)&la[row * BK + s * 8]     = p0;
        *(ux4*)&la[row * BK + s * 8 + 4] = p1;
      }
    }
    if constexpr (WB16) {
      const u16* wp = (const u16*)Wv + (size_t)n0 * K + k0;
      #pragma unroll
      for (int i = 0; i < 4; ++i) {
        int c = i * 256 + tid, row = c >> 3, cc = c & 7;
        int g = cc ^ (row & 7);
        gl_lds(wp + (size_t)row * K + g * 8, &lb[c * 8]);
      }
    } else {
      const float* wp = (const float*)Wv + (size_t)n0 * K + k0;
      #pragma unroll
      for (int i = 0; i < 4; ++i) {
        int c = i * 256 + tid, row = c >> 3, cc = c & 7;
        fx4 v0 = *(const fx4*)&wp[(size_t)row * K + cc * 8];
        fx4 v1 = *(const fx4*)&wp[(size_t)row * K + cc * 8 + 4];
        ux4 p0, p1;
        p0[0]=f2bf(v0[0]); p0[1]=f2bf(v0[1]); p0[2]=f2bf(v0[2]); p0[3]=f2bf(v0[3]);
        p1[0]=f2bf(v1[0]); p1[1]=f2bf(v1[1]); p1[2]=f2bf(v1[2]); p1[3]=f2bf(v1[3]);
        int s = cc ^ (row & 7);
        *(ux4*)&lb[row * BK + s * 8]     = p0;
        *(ux4*)&lb[row * BK + s * 8 + 4] = p1;
      }
    }
    __syncthreads();
    #pragma unroll
    for (int ks = 0; ks < 2; ++ks) {
      short8 af[4], bfg[4];
      #pragma unroll
      for (int t = 0; t < 4; ++t) {
        int arow = wm * 64 + t * 16 + l16;
        int brow = (t & 2) * 32 + wn * 32 + (t & 1) * 16 + l16;
        int cc = (ks * 4 + quad) ^ sw;
        af[t]  = *(const short8*)&la[arow * BK + cc * 8];
        bfg[t] = *(const short8*)&lb[brow * BK + cc * 8];
      }
      #pragma unroll
      for (int mt = 0; mt < 4; ++mt)
        #pragma unroll
        for (int nt = 0; nt < 4; ++nt)
          acc[mt][nt] = __builtin_amdgcn_mfma_f32_16x16x32_bf16(af[mt], bfg[nt], acc[mt][nt], 0, 0, 0);
    }
  }

  if constexpr (MODE == 0) {
    float* of = (float*)o0;
    #pragma unroll
    for (int nt = 0; nt < 4; ++nt) {
      int col = n0 + (nt & 2) * 32 + wn * 32 + (nt & 1) * 16 + l16;
      float bz = bias[col];
      #pragma unroll
      for (int mt = 0; mt < 4; ++mt) {
        int row = m0 + wm * 64 + mt * 16 + quad * 4;
        #pragma unroll
        for (int r = 0; r < 4; ++r)
          of[(size_t)(row + r) * N + col] = acc[mt][nt][r] + bz;
      }
    }
  } else {
    const int which = n0 >> 11;
    const int head  = (n0 >> 7) & 15;
    const int b     = m0 >> 11;
    const int bh    = b * NH + head;
    if (which == 2) {
      #pragma unroll
      for (int nt = 0; nt < 4; ++nt) {
        int dcol = (nt & 2) * 32 + wn * 32 + (nt & 1) * 16 + l16;
        float bz = bias[n0 + dcol];
        #pragma unroll
        for (int mt = 0; mt < 4; ++mt) {
          int srow = (m0 & (S_LEN - 1)) + wm * 64 + mt * 16 + quad * 4;
          ux4 pk;
          #pragma unroll
          for (int r = 0; r < 4; ++r) pk[r] = f2bf(acc[mt][nt][r] + bz);
          *(ux4*)&o2[((size_t)bh * HD + dcol) * S_LEN + srow] = pk;  // V^T
        }
      }
    } else {
      // Q or K with fused RoPE: pair (i, i+64) = acc[..][nt] / acc[..][nt+2]
      u16* buf = (which == 0) ? (u16*)o0 : o1;
      #pragma unroll
      for (int nt = 0; nt < 2; ++nt) {
        int i = wn * 32 + nt * 16 + l16;            // 0..63
        // invf2 = 10000^(-i/64) / (2*pi): angle in revolutions per srow
        float invf2 = exp2f((float)i * -0.20762050594f) * INV2PI;
        float bz1 = bias[n0 + i];
        float bz2 = bias[n0 + i + 64];
        #pragma unroll
        for (int mt = 0; mt < 4; ++mt) {
          int srow = (m0 & (S_LEN - 1)) + wm * 64 + mt * 16 + quad * 4;
          size_t base = ((size_t)bh * S_LEN + srow) * HD + i;
          #pragma unroll
          for (int r = 0; r < 4; ++r) {
            float sn, cs;
            fast_sincos((float)(srow + r) * invf2, sn, cs);
            float v1 = acc[mt][nt][r] + bz1;
            float v2 = acc[mt][nt + 2][r] + bz2;
            buf[base + (size_t)r * HD]      = f2bf(v1 * cs - v2 * sn);
            buf[base + (size_t)r * HD + 64] = f2bf(v2 * cs + v1 * sn);
          }
        }
      }
    }
  }
}

// ---------------------------------------------------------------------------
// Transposed online-softmax tile step with defer-max (T13). S^T in C-layout:
// lane owns q-row=l16, 16 keys = snt*16 + quad*4 + r in registers. Row reduce
// = in-register tree + 2 shuffles. Defer the O-rescale when the tile max is
// within 8 (log2) of the running max (wave-uniform via __all).
// P -> LDS [q][key] stride 72: row base l16*36 dwords spreads rows across
// banks (stride-64 repack measured ~8-way conflicted -> reverted).
// ---------------------------------------------------------------------------
__device__ __forceinline__ void soft_tile_t(fx4 s[4], float& m, float& l, fx4* o,
                                            u16* lp, bool mask, int qrow, int k0,
                                            int l16, int quad)
{
  #pragma unroll
  for (int snt = 0; snt < 4; ++snt)
    #pragma unroll
    for (int r = 0; r < 4; ++r) {
      float v = s[snt][r] * SC2;
      if (mask && (k0 + snt * 16 + quad * 4 + r > qrow)) v = NEG;
      s[snt][r] = v;
    }
  float mx = s[0][0];
  #pragma unroll
  for (int snt = 0; snt < 4; ++snt)
    #pragma unroll
    for (int r = 0; r < 4; ++r) mx = fmaxf(mx, s[snt][r]);
  mx = fmaxf(mx, __shfl_xor(mx, 16, 64));
  mx = fmaxf(mx, __shfl_xor(mx, 32, 64));

  const bool defer = __all(mx <= m + 8.f);   // wave-uniform
  float al = 1.f;
  if (!defer) {
    float mn = fmaxf(m, mx);
    al = exp2f(m - mn);
    m = mn;
  }
  float rs = 0.f;
  #pragma unroll
  for (int snt = 0; snt < 4; ++snt)
    #pragma unroll
    for (int r = 0; r < 4; ++r) {
      float pz = exp2f(s[snt][r] - m);
      s[snt][r] = pz;
      rs += pz;
    }
  rs += __shfl_xor(rs, 16, 64);
  rs += __shfl_xor(rs, 32, 64);
  l = l * al + rs;
  if (!defer) {
    #pragma unroll
    for (int nd = 0; nd < 8; ++nd)
      #pragma unroll
      for (int r = 0; r < 4; ++r) o[nd][r] *= al;
  }
  #pragma unroll
  for (int snt = 0; snt < 4; ++snt) {
    ux4 pk;
    #pragma unroll
    for (int r = 0; r < 4; ++r) pk[r] = f2bf(s[snt][r]);
    *(ux4*)&lp[l16 * 72 + snt * 16 + quad * 4] = pk;   // 8B write
  }
}

// ---------------------------------------------------------------------------
// Flash attention (causal), UNPAIRED q-tiles -- the R4-proven configuration
// (best attn measured): XCD-grouped bh, ascending qt (LPT variant measured
// worse), 3 blocks/CU, stride-72 P. Transposed pipeline: S^T = K·Q^T,
// O^T = V^T·P^T, per-lane-scalar softmax, defer-max.
// Grid: flat 1024; w%8 = XCD (confirmed FETCH 144->36 MB), each XCD owns
// 4 bh (4 MB K/V = one L2).
// NEW (T5): s_setprio(1) around the MFMA clusters -- waves within/across the
// 3 resident blocks diverge between barriers, so the CU scheduler can favor
// MFMA-issuing waves (m191: +4-7% on attn; sole new delta this round).
// ---------------------------------------------------------------------------
__global__ __launch_bounds__(256, 3)
void attn_kernel(const u16* __restrict__ qbuf, const u16* __restrict__ kbuf,
                 const u16* __restrict__ vtbuf, u16* __restrict__ ctx)
{
  __shared__ u16 lk[64 * 128];     // K tile  [key][d],  swizzled chunks
  __shared__ u16 lv[128 * 64];     // V^T tile [d][key], swizzled chunks
  __shared__ u16 lp[4][16 * 72];   // per-wave P [q][key]
  const int tid = threadIdx.x, lane = tid & 63, wv = tid >> 6;
  const int quad = lane >> 4, l16 = lane & 15;
  const int w = blockIdx.x;
  const int bh = (w & 7) * 4 + ((w >> 3) >> 5);   // XCD-grouped head
  const int qt = (w >> 3) & 31;                   // q-tile 0..31 (ascending)
  const int head = bh & 15, b = bh >> 4;
  const int s8 = l16 & 7;          // frag-read swizzle index

  short8 qh[4];
  {
    const size_t q_ = ((size_t)bh * S_LEN + qt * 64 + wv * 16 + l16) * HD;
    #pragma unroll
    for (int kd = 0; kd < 4; ++kd)
      qh[kd] = *(const short8*)&qbuf[q_ + kd * 32 + quad * 8];
  }

  fx4 oh[8] = {};
  float m = NEG, l = 0.f;
  const int qrow = qt * 64 + wv * 16 + l16;

  for (int kt = 0; kt <= qt; ++kt) {
    if (kt) __syncthreads();                 // WAR vs previous compute
    {
      const u16* kg = kbuf + ((size_t)bh * S_LEN + kt * 64) * HD;
      const u16* vg = vtbuf + (size_t)bh * HD * S_LEN + kt * 64;
      #pragma unroll
      for (int i = 0; i < 4; ++i) {          // K tile: 64 rows x 16 chunks
        int c = i * 256 + tid;
        int row = c >> 4, cc = c & 15;
        int g = cc ^ (row & 7);
        gl_lds(kg + (size_t)row * HD + g * 8, &lk[c * 8]);
      }
      #pragma unroll
      for (int i = 0; i < 4; ++i) {          // V^T tile: 128 rows x 8 chunks
        int c = i * 256 + tid;
        int row = c >> 3, cc = c & 7;
        int g = cc ^ (row & 7);
        gl_lds(vg + (size_t)row * S_LEN + g * 8, &lv[c * 8]);
      }
    }
    __syncthreads();                         // RAW: drain stage

    // S^T = K·Q^T
    fx4 sh[4] = {};
    __builtin_amdgcn_s_setprio(1);
    #pragma unroll
    for (int snt = 0; snt < 4; ++snt) {
      #pragma unroll
      for (int kd = 0; kd < 4; ++kd) {
        int cc = (kd * 4 + quad) ^ s8;
        short8 kf = *(const short8*)&lk[(snt * 16 + l16) * 128 + cc * 8];
        sh[snt] = __builtin_amdgcn_mfma_f32_16x16x32_bf16(kf, qh[kd], sh[snt], 0, 0, 0);
      }
    }
    __builtin_amdgcn_s_setprio(0);

    soft_tile_t(sh, m, l, oh, lp[wv], kt == qt, qrow, kt * 64, l16, quad);

    // O^T += V^T·P^T
    __builtin_amdgcn_s_setprio(1);
    #pragma unroll
    for (int kk = 0; kk < 2; ++kk) {
      short8 ph = *(const short8*)&lp[wv][l16 * 72 + kk * 32 + quad * 8];
      #pragma unroll
      for (int nd = 0; nd < 8; ++nd) {
        int cc = (kk * 4 + quad) ^ s8;
        short8 vf = *(const short8*)&lv[(nd * 16 + l16) * 64 + cc * 8];
        oh[nd] = __builtin_amdgcn_mfma_f32_16x16x32_bf16(vf, ph, oh[nd], 0, 0, 0);
      }
    }
    __builtin_amdgcn_s_setprio(0);
  }

  // O^T regs: lane q=l16, d = nd*16 + quad*4 + r  -> 8B packed stores
  {
    float ih = 1.f / l;
    size_t rh = ((size_t)b * S_LEN + qt * 64 + wv * 16 + l16) * DM + head * HD;
    #pragma unroll
    for (int nd = 0; nd < 8; ++nd) {
      ux4 ph;
      #pragma unroll
      for (int r = 0; r < 4; ++r) ph[r] = f2bf(oh[nd][r] * ih);
      *(ux4*)&ctx[rh + nd * 16 + quad * 4] = ph;
    }
  }
}

// ---------------------------------------------------------------------------
extern "C" void kernel_launch(void* const* d_in, const int* in_sizes, int n_in,
                              void* d_out, int out_size, void* d_ws, size_t ws_size,
                              hipStream_t stream)
{
  const float* x    = (const float*)d_in[0];
  const float* Wqkv = (const float*)d_in[2];
  const float* bqkv = (const float*)d_in[3];
  const float* Wout = (const float*)d_in[4];
  const float* bout = (const float*)d_in[5];
  float* out = (float*)d_out;

  constexpr size_t XB_E = (size_t)4096 * 2048;   // 8.39M elems
  constexpr size_t WQ_E = (size_t)6144 * 2048;
  constexpr size_t WO_E = (size_t)2048 * 2048;
  constexpr size_t NEED = (XB_E + WQ_E + WO_E + 3 * XB_E) * 2;  // ~101 MB

  if (ws_size >= NEED) {
    u16* xb  = (u16*)d_ws;
    u16* wqb = xb + XB_E;
    u16* wob = wqb + WQ_E;
    u16* qb  = wob + WO_E;
    u16* kb  = qb + XB_E;
    u16* vb  = kb + XB_E;
    u16* ctx = xb;                 // xb dead after QKV GEMM; reuse for ctx

    cvt3_kernel<<<dim3(24576), 256, 0, stream>>>(x, Wqkv, Wout, xb, wqb, wob);
    gemm_bt<4096, 6144, 2048, 1, true, true><<<dim3(48, 32), 256, 0, stream>>>(
        xb, wqb, bqkv, qb, kb, vb);
    attn_kernel<<<dim3(1024), 256, 0, stream>>>(qb, kb, vb, ctx);
    gemm_bt<4096, 2048, 2048, 0, true, true><<<dim3(16, 32), 256, 0, stream>>>(
        ctx, wob, bout, out, nullptr, nullptr);
  } else {
    // fallback: 48 MiB ws, fused fp32->bf16 staging in GEMMs, ctx in d_out
    u16* qb = (u16*)d_ws;
    u16* kb = qb + XB_E;
    u16* vb = kb + XB_E;
    u16* ctx = (u16*)d_out;
    float* tmpo = (float*)d_ws;   // over dead qb/kb at out-proj time

    gemm_bt<4096, 6144, 2048, 1, false, false><<<dim3(48, 32), 256, 0, stream>>>(
        x, Wqkv, bqkv, qb, kb, vb);
    attn_kernel<<<dim3(1024), 256, 0, stream>>>(qb, kb, vb, ctx);
    gemm_bt<4096, 2048, 2048, 0, true, false><<<dim3(16, 32), 256, 0, stream>>>(
        ctx, Wout, bout, tmpo, nullptr, nullptr);
    hipMemcpyAsync(out, tmpo, (size_t)out_size * sizeof(float),
                   hipMemcpyDeviceToDevice, stream);
  }
}